// Round 5
// baseline (837.808 us; speedup 1.0000x reference)
//
#include <hip/hip_runtime.h>
#include <stdint.h>

#define N_TOK 4096
#define H_Q   32
#define H_KV  8
#define DH    128
#define SEQ   2048
#define BATCH (N_TOK / SEQ)
#define GRP   (H_Q / H_KV)
#define QTILE 32     // q rows per block (shared by 4 heads)
#define KVT   32     // kv tile
#define NQT   (SEQ / QTILE)

#define KP 136   // K_lds row pitch (bf16)
#define VP 40    // V_lds^T row pitch (bf16)
#define PP 40    // P_lds row pitch

typedef __attribute__((ext_vector_type(8))) short bf16x8;
typedef __attribute__((ext_vector_type(4))) float f32x4;
typedef __attribute__((ext_vector_type(4))) int   i32x4;

__device__ __forceinline__ uint16_t f2bf(float x) {
  uint32_t u = __float_as_uint(x);
  u += 0x7FFFu + ((u >> 16) & 1u);   // RNE
  return (uint16_t)(u >> 16);
}
__device__ __forceinline__ uint32_t pk2(float a, float b) {
  return (uint32_t)f2bf(a) | ((uint32_t)f2bf(b) << 16);
}

// Block: 32 q-rows x 4 q-heads of one hkv group. 8 waves (512 thr);
// wave w: head = w&3, m-tile = w>>2. KV tiles of 32, double-buffered LDS,
// ONE barrier per tile, register-prefetch of tile t+1 during compute of t.
// Grid: x = (hkv + 8*b) [16], y -> qt = (y*23)&63 scatter so co-resident
// blocks mix heavy/light causal workloads (balance).
//
// SWAPPED MFMA: S^T = mfma(A=K, B=Q^T) -> D[kv][q]: lane owns q-row (l&15),
// 8 kv values in-register -> softmax is 7 in-lane ops + 2 shfl.
// PV: O^T = mfma(A=V^T, B=P^T) -> D[d][q] -> vectorized f32x4 stores.
__global__ __launch_bounds__(512, 6) void attn_fwd(
    const float* __restrict__ q, const float* __restrict__ k,
    const float* __restrict__ v, float* __restrict__ out)
{
  const int xb  = blockIdx.x;
  const int hkv = xb & 7;
  const int b   = xb >> 3;
  const int qt  = (int)((blockIdx.y * 23u) & 63u);   // balance scatter
  const int q0  = qt * QTILE;
  const int tid = threadIdx.x;
  const int wid = tid >> 6;
  const int lane = tid & 63;
  const int lg = lane >> 4;
  const int lr = lane & 15;
  const int h  = hkv * GRP + (wid & 3);
  const int mt = wid >> 2;

  __shared__ uint16_t K_lds[2][KVT * KP];
  __shared__ uint16_t V_lds[2][DH * VP];
  __shared__ uint16_t P_lds[8][16 * PP];

  // ---- Q fragment (B-operand), pre-scaled ----
  const int qrow = q0 + mt * 16 + lr;
  bf16x8 qf[4];
  {
    const float* qp = q + ((size_t)(b * SEQ + qrow) * H_Q + h) * DH + lg * 8;
    const float sc = 0.08838834764831845f;  // 1/sqrt(128)
#pragma unroll
    for (int dblk = 0; dblk < 4; ++dblk) {
      f32x4 f0 = *(const f32x4*)(qp + dblk * 32);
      f32x4 f1 = *(const f32x4*)(qp + dblk * 32 + 4);
      i32x4 w;
      w[0] = pk2(f0[0] * sc, f0[1] * sc);
      w[1] = pk2(f0[2] * sc, f0[3] * sc);
      w[2] = pk2(f1[0] * sc, f1[1] * sc);
      w[3] = pk2(f1[2] * sc, f1[3] * sc);
      qf[dblk] = *(bf16x8*)&w;
    }
  }

  // ---- staging roles + bases ----
  const bool isK = (tid < 256);
  const int krow = tid >> 3, kc0 = (tid & 7) * 16;          // K: 64B per thread
  const int t2 = tid & 255;
  const int rr = t2 & 31, cc = t2 >> 5, vc = (cc + rr) & 7; // V: scrambled kv-group
  const size_t kvstep = (size_t)KVT * H_KV * DH;
  const size_t vstep  = (size_t)H_KV * DH;
  const float* kbase = k + ((size_t)(b * SEQ + krow) * H_KV + hkv) * DH + kc0;
  const float* vbase = v + ((size_t)(b * SEQ + 4 * vc) * H_KV + hkv) * DH + 4 * rr;

  f32x4 r0, r1, r2, r3;  // prefetch registers
  auto issue = [&](int t) {
    if (isK) {
      const float* p = kbase + (size_t)t * kvstep;
      r0 = *(const f32x4*)(p);
      r1 = *(const f32x4*)(p + 4);
      r2 = *(const f32x4*)(p + 8);
      r3 = *(const f32x4*)(p + 12);
    } else {
      const float* p = vbase + (size_t)t * kvstep;
      r0 = *(const f32x4*)(p);
      r1 = *(const f32x4*)(p + vstep);
      r2 = *(const f32x4*)(p + 2 * vstep);
      r3 = *(const f32x4*)(p + 3 * vstep);
    }
  };
  auto commit = [&](int buf) {
    if (isK) {
      i32x4 w0, w1;
      w0[0] = pk2(r0[0], r0[1]); w0[1] = pk2(r0[2], r0[3]);
      w0[2] = pk2(r1[0], r1[1]); w0[3] = pk2(r1[2], r1[3]);
      w1[0] = pk2(r2[0], r2[1]); w1[1] = pk2(r2[2], r2[3]);
      w1[2] = pk2(r3[0], r3[1]); w1[3] = pk2(r3[2], r3[3]);
      *(i32x4*)&K_lds[buf][krow * KP + kc0]     = w0;
      *(i32x4*)&K_lds[buf][krow * KP + kc0 + 8] = w1;
    } else {
#pragma unroll
      for (int dd = 0; dd < 4; ++dd) {
        uint2 w;
        w.x = pk2(r0[dd], r1[dd]);
        w.y = pk2(r2[dd], r3[dd]);
        *(uint2*)&V_lds[buf][(4 * rr + dd) * VP + 4 * vc] = w;
      }
    }
  };

  f32x4 o[8];
#pragma unroll
  for (int i = 0; i < 8; ++i) o[i] = (f32x4){0.f, 0.f, 0.f, 0.f};
  float m_i = -1e30f, l_i = 0.f;

  const int nt = qt + 1;
  const float L2E = 1.4426950408889634f;

  issue(0);
  for (int t = 0; t < nt; ++t) {
    const int buf = t & 1;
    commit(buf);                       // vmcnt wait happens here
    if (t + 1 < nt) issue(t + 1);      // loads land during compute below
    __syncthreads();                   // single barrier per tile (dbuf LDS)

    const int kv0 = t * KVT;

    // ---- S^T = K Q^T ----
    f32x4 s0 = (f32x4){0.f, 0.f, 0.f, 0.f};
    f32x4 s1 = (f32x4){0.f, 0.f, 0.f, 0.f};
    const uint16_t* Kb = K_lds[buf];
#pragma unroll
    for (int dblk = 0; dblk < 4; ++dblk) {
      bf16x8 kb0 = *(const bf16x8*)&Kb[lr * KP + dblk * 32 + lg * 8];
      bf16x8 kb1 = *(const bf16x8*)&Kb[(16 + lr) * KP + dblk * 32 + lg * 8];
      s0 = __builtin_amdgcn_mfma_f32_16x16x32_bf16(kb0, qf[dblk], s0, 0, 0, 0);
      s1 = __builtin_amdgcn_mfma_f32_16x16x32_bf16(kb1, qf[dblk], s1, 0, 0, 0);
    }

    // ---- softmax (lane-local row); mask only on the diagonal tile ----
    float p[8];
    if (t == nt - 1) {
#pragma unroll
      for (int i = 0; i < 4; ++i) {
        p[i]     = (kv0 + lg * 4 + i      <= qrow) ? s0[i] : -1e30f;
        p[4 + i] = (kv0 + 16 + lg * 4 + i <= qrow) ? s1[i] : -1e30f;
      }
    } else {
#pragma unroll
      for (int i = 0; i < 4; ++i) { p[i] = s0[i]; p[4 + i] = s1[i]; }
    }
    float mx = fmaxf(fmaxf(fmaxf(p[0], p[1]), fmaxf(p[2], p[3])),
                     fmaxf(fmaxf(p[4], p[5]), fmaxf(p[6], p[7])));
    mx = fmaxf(mx, __shfl_xor(mx, 16));
    mx = fmaxf(mx, __shfl_xor(mx, 32));
    if (mx > m_i) {                    // exact defer: r==1 when skipped
      const float rs = exp2f((m_i - mx) * L2E);
      l_i *= rs;
#pragma unroll
      for (int dt = 0; dt < 8; ++dt) {
        o[dt][0] *= rs; o[dt][1] *= rs; o[dt][2] *= rs; o[dt][3] *= rs;
      }
      m_i = mx;
    }
#pragma unroll
    for (int j = 0; j < 8; ++j) p[j] = exp2f((p[j] - m_i) * L2E);
    float sum = ((p[0] + p[1]) + (p[2] + p[3])) + ((p[4] + p[5]) + (p[6] + p[7]));
    sum += __shfl_xor(sum, 16);
    sum += __shfl_xor(sum, 32);
    l_i += sum;

    // ---- stage P[q][kv] (per-wave, no barrier) ----
    {
      uint2 w0, w1;
      w0.x = pk2(p[0], p[1]); w0.y = pk2(p[2], p[3]);
      w1.x = pk2(p[4], p[5]); w1.y = pk2(p[6], p[7]);
      *(uint2*)&P_lds[wid][lr * PP + lg * 4]      = w0;
      *(uint2*)&P_lds[wid][lr * PP + 16 + lg * 4] = w1;
    }

    // ---- O^T += V^T P^T ----
    bf16x8 pf = *(const bf16x8*)&P_lds[wid][lr * PP + lg * 8];
    const uint16_t* Vb = V_lds[buf];
#pragma unroll
    for (int dt = 0; dt < 8; ++dt) {
      bf16x8 vb = *(const bf16x8*)&Vb[(dt * 16 + lr) * VP + lg * 8];
      o[dt] = __builtin_amdgcn_mfma_f32_16x16x32_bf16(vb, pf, o[dt], 0, 0, 0);
    }
  }

  // ---- epilogue ----
  const float inv = 1.0f / l_i;
  float* op = out + ((size_t)(b * SEQ + qrow) * H_Q + h) * DH + lg * 4;
#pragma unroll
  for (int dt = 0; dt < 8; ++dt) {
    f32x4 w = o[dt];
    w[0] *= inv; w[1] *= inv; w[2] *= inv; w[3] *= inv;
    *(f32x4*)(op + dt * 16) = w;
  }
}

// ---- KV cache: copy base cache, then scatter new k/v rows by slot ----
__global__ __launch_bounds__(256) void copy_caches(
    const f32x4* __restrict__ kc_in, const f32x4* __restrict__ vc_in,
    f32x4* __restrict__ kc_out, f32x4* __restrict__ vc_out)
{
  const size_t i = (size_t)blockIdx.x * 256 + threadIdx.x;
  kc_out[i] = kc_in[i];
  vc_out[i] = vc_in[i];
}

__global__ __launch_bounds__(256) void scatter_kv(
    const f32x4* __restrict__ kin, const f32x4* __restrict__ vin,
    const int* __restrict__ slot, f32x4* __restrict__ kc_out,
    f32x4* __restrict__ vc_out)
{
  const int row = blockIdx.x;
  const int s = slot[row];
  if (s < 0) return;
  const int t = threadIdx.x;  // 256 threads x float4 = 1024 floats/row
  kc_out[(size_t)s * 256 + t] = kin[(size_t)row * 256 + t];
  vc_out[(size_t)s * 256 + t] = vin[(size_t)row * 256 + t];
}

extern "C" void kernel_launch(void* const* d_in, const int* in_sizes, int n_in,
                              void* d_out, int out_size, void* d_ws, size_t ws_size,
                              hipStream_t stream) {
  const float* q  = (const float*)d_in[0];
  const float* k  = (const float*)d_in[1];
  const float* v  = (const float*)d_in[2];
  const float* kc = (const float*)d_in[3];
  const float* vc = (const float*)d_in[4];
  const int* slot = (const int*)d_in[5];

  float* out    = (float*)d_out;
  float* kc_out = out + (size_t)N_TOK * H_Q * DH;
  float* vc_out = kc_out + (size_t)N_TOK * H_KV * DH;

  copy_caches<<<dim3((N_TOK * H_KV * DH / 4) / 256), 256, 0, stream>>>(
      (const f32x4*)kc, (const f32x4*)vc, (f32x4*)kc_out, (f32x4*)vc_out);
  scatter_kv<<<dim3(N_TOK), 256, 0, stream>>>(
      (const f32x4*)k, (const f32x4*)v, slot, (f32x4*)kc_out, (f32x4*)vc_out);
  attn_fwd<<<dim3(H_KV * BATCH, NQT), 512, 0, stream>>>(q, k, v, out);
}

// Round 6
// 415.999 us; speedup vs baseline: 2.0140x; 2.0140x over previous
//
#include <hip/hip_runtime.h>
#include <stdint.h>

#define N_TOK 4096
#define H_Q   32
#define H_KV  8
#define DH    128
#define SEQ   2048
#define BATCH (N_TOK / SEQ)
#define GRP   (H_Q / H_KV)
#define QTILE 32     // q rows per block (shared by 4 heads)
#define KVT   32     // kv tile
#define NQT   (SEQ / QTILE)

#define KP 136   // K_lds row pitch (bf16)
#define VP 40    // V_lds^T row pitch (bf16)
#define PP 40    // P_lds row pitch

typedef __attribute__((ext_vector_type(8))) short bf16x8;
typedef __attribute__((ext_vector_type(4))) float f32x4;
typedef __attribute__((ext_vector_type(4))) int   i32x4;

__device__ __forceinline__ uint16_t f2bf(float x) {
  uint32_t u = __float_as_uint(x);
  u += 0x7FFFu + ((u >> 16) & 1u);   // RNE
  return (uint16_t)(u >> 16);
}
__device__ __forceinline__ uint32_t pk2(float a, float b) {
  return (uint32_t)f2bf(a) | ((uint32_t)f2bf(b) << 16);
}

// Block: 32 q-rows x 4 q-heads of one hkv group. 8 waves (512 thr);
// wave w: head = w&3, m-tile = w>>2. KV tiles of 32 staged once per block
// (K by waves 0-3, V by waves 4-7). Straight-line staging, NO prefetch
// registers (round-5 lambda prefetch spilled to scratch: 2.17 GB traffic).
// Grid: x = (hkv + 8*b) [16], y -> qt = (y*23)&63 scatter so co-resident
// blocks mix heavy/light causal workloads (validated: occupancy 22->52%).
//
// SWAPPED MFMA: S^T = mfma(A=K, B=Q^T) -> D[kv][q]: lane owns q-row (l&15),
// 8 kv values in-register -> softmax is 7 in-lane ops + 2 shfl.
// PV: O^T = mfma(A=V^T, B=P^T) -> D[d][q] -> vectorized f32x4 stores.
__global__ __launch_bounds__(512) void attn_fwd(
    const float* __restrict__ q, const float* __restrict__ k,
    const float* __restrict__ v, float* __restrict__ out)
{
  const int xb  = blockIdx.x;
  const int hkv = xb & 7;
  const int b   = xb >> 3;
  const int qt  = (int)((blockIdx.y * 23u) & 63u);   // balance scatter
  const int q0  = qt * QTILE;
  const int tid = threadIdx.x;
  const int wid = tid >> 6;
  const int lane = tid & 63;
  const int lg = lane >> 4;
  const int lr = lane & 15;
  const int h  = hkv * GRP + (wid & 3);
  const int mt = wid >> 2;

  __shared__ uint16_t K_lds[KVT * KP];      // [kv][d]
  __shared__ uint16_t V_lds[DH * VP];       // [d][kv] (transposed)
  __shared__ uint16_t P_lds[8][16 * PP];    // per-wave P staging [q][kv]

  // ---- Q fragment (B-operand), pre-scaled ----
  const int qrow = q0 + mt * 16 + lr;
  bf16x8 qf[4];
  {
    const float* qp = q + ((size_t)(b * SEQ + qrow) * H_Q + h) * DH + lg * 8;
    const float sc = 0.08838834764831845f;  // 1/sqrt(128)
#pragma unroll
    for (int dblk = 0; dblk < 4; ++dblk) {
      f32x4 f0 = *(const f32x4*)(qp + dblk * 32);
      f32x4 f1 = *(const f32x4*)(qp + dblk * 32 + 4);
      i32x4 w;
      w[0] = pk2(f0[0] * sc, f0[1] * sc);
      w[1] = pk2(f0[2] * sc, f0[3] * sc);
      w[2] = pk2(f1[0] * sc, f1[1] * sc);
      w[3] = pk2(f1[2] * sc, f1[3] * sc);
      qf[dblk] = *(bf16x8*)&w;
    }
  }

  f32x4 o[8];
#pragma unroll
  for (int i = 0; i < 8; ++i) o[i] = (f32x4){0.f, 0.f, 0.f, 0.f};
  float m_i = -1e30f, l_i = 0.f;

  const int nt = qt + 1;
  const float L2E = 1.4426950408889634f;

  for (int t = 0; t < nt; ++t) {
    const int kv0 = t * KVT;
    __syncthreads();  // protect LDS from previous iteration's readers

    if (tid < 256) {
      // ---- stage K tile [32][128] f32 -> bf16 LDS (waves 0-3) ----
      const int row = tid >> 3;
      const int c0 = (tid & 7) * 16;
      const float* kp = k + ((size_t)(b * SEQ + kv0 + row) * H_KV + hkv) * DH + c0;
      f32x4 f0 = *(const f32x4*)(kp + 0);
      f32x4 f1 = *(const f32x4*)(kp + 4);
      f32x4 f2 = *(const f32x4*)(kp + 8);
      f32x4 f3 = *(const f32x4*)(kp + 12);
      i32x4 w0, w1;
      w0[0] = pk2(f0[0], f0[1]); w0[1] = pk2(f0[2], f0[3]);
      w0[2] = pk2(f1[0], f1[1]); w0[3] = pk2(f1[2], f1[3]);
      w1[0] = pk2(f2[0], f2[1]); w1[1] = pk2(f2[2], f2[3]);
      w1[2] = pk2(f3[0], f3[1]); w1[3] = pk2(f3[2], f3[3]);
      *(i32x4*)&K_lds[row * KP + c0]     = w0;
      *(i32x4*)&K_lds[row * KP + c0 + 8] = w1;
    } else {
      // ---- stage V tile transposed [d][kv], scrambled kv-group (waves 4-7) ----
      const int t2 = tid - 256;
      const int rr = t2 & 31;             // d-group (d = 4*rr..+3)
      const int cc = t2 >> 5;             // 0..7
      const int c  = (cc + rr) & 7;       // scrambled kv-group (bijective per rr)
      const float* vp = v + ((size_t)(b * SEQ + kv0 + 4 * c) * H_KV + hkv) * DH + 4 * rr;
      const size_t vstep = (size_t)H_KV * DH;
      f32x4 r0 = *(const f32x4*)(vp);
      f32x4 r1 = *(const f32x4*)(vp + vstep);
      f32x4 r2 = *(const f32x4*)(vp + 2 * vstep);
      f32x4 r3 = *(const f32x4*)(vp + 3 * vstep);
#pragma unroll
      for (int dd = 0; dd < 4; ++dd) {
        uint2 w;
        w.x = pk2(r0[dd], r1[dd]);
        w.y = pk2(r2[dd], r3[dd]);
        *(uint2*)&V_lds[(4 * rr + dd) * VP + 4 * c] = w;
      }
    }
    __syncthreads();

    // ---- S^T = K Q^T (D[kv][q]; s0: kv0+lg*4+i, s1: +16) ----
    f32x4 s0 = (f32x4){0.f, 0.f, 0.f, 0.f};
    f32x4 s1 = (f32x4){0.f, 0.f, 0.f, 0.f};
#pragma unroll
    for (int dblk = 0; dblk < 4; ++dblk) {
      bf16x8 kb0 = *(const bf16x8*)&K_lds[lr * KP + dblk * 32 + lg * 8];
      bf16x8 kb1 = *(const bf16x8*)&K_lds[(16 + lr) * KP + dblk * 32 + lg * 8];
      s0 = __builtin_amdgcn_mfma_f32_16x16x32_bf16(kb0, qf[dblk], s0, 0, 0, 0);
      s1 = __builtin_amdgcn_mfma_f32_16x16x32_bf16(kb1, qf[dblk], s1, 0, 0, 0);
    }

    // ---- softmax (lane-local row); mask only on the diagonal tile ----
    float p[8];
    if (t == nt - 1) {
#pragma unroll
      for (int i = 0; i < 4; ++i) {
        p[i]     = (kv0 + lg * 4 + i      <= qrow) ? s0[i] : -1e30f;
        p[4 + i] = (kv0 + 16 + lg * 4 + i <= qrow) ? s1[i] : -1e30f;
      }
    } else {
#pragma unroll
      for (int i = 0; i < 4; ++i) { p[i] = s0[i]; p[4 + i] = s1[i]; }
    }
    float mx = fmaxf(fmaxf(fmaxf(p[0], p[1]), fmaxf(p[2], p[3])),
                     fmaxf(fmaxf(p[4], p[5]), fmaxf(p[6], p[7])));
    mx = fmaxf(mx, __shfl_xor(mx, 16));
    mx = fmaxf(mx, __shfl_xor(mx, 32));
    if (mx > m_i) {                    // exact defer: rescale only if max grew
      const float rs = exp2f((m_i - mx) * L2E);
      l_i *= rs;
#pragma unroll
      for (int dt = 0; dt < 8; ++dt) {
        o[dt][0] *= rs; o[dt][1] *= rs; o[dt][2] *= rs; o[dt][3] *= rs;
      }
      m_i = mx;
    }
#pragma unroll
    for (int j = 0; j < 8; ++j) p[j] = exp2f((p[j] - m_i) * L2E);
    float sum = ((p[0] + p[1]) + (p[2] + p[3])) + ((p[4] + p[5]) + (p[6] + p[7]));
    sum += __shfl_xor(sum, 16);
    sum += __shfl_xor(sum, 32);
    l_i += sum;

    // ---- stage P[q][kv] (per-wave, no barrier) ----
    {
      uint2 w0, w1;
      w0.x = pk2(p[0], p[1]); w0.y = pk2(p[2], p[3]);
      w1.x = pk2(p[4], p[5]); w1.y = pk2(p[6], p[7]);
      *(uint2*)&P_lds[wid][lr * PP + lg * 4]      = w0;
      *(uint2*)&P_lds[wid][lr * PP + 16 + lg * 4] = w1;
    }

    // ---- O^T += V^T P^T (D[d][q]) ----
    bf16x8 pf = *(const bf16x8*)&P_lds[wid][lr * PP + lg * 8];
#pragma unroll
    for (int dt = 0; dt < 8; ++dt) {
      bf16x8 vb = *(const bf16x8*)&V_lds[(dt * 16 + lr) * VP + lg * 8];
      o[dt] = __builtin_amdgcn_mfma_f32_16x16x32_bf16(vb, pf, o[dt], 0, 0, 0);
    }
  }

  // ---- epilogue: out[qrow][d] = O^T / l ; d = dt*16 + lg*4 + i ----
  const float inv = 1.0f / l_i;
  float* op = out + ((size_t)(b * SEQ + qrow) * H_Q + h) * DH + lg * 4;
#pragma unroll
  for (int dt = 0; dt < 8; ++dt) {
    f32x4 w = o[dt];
    w[0] *= inv; w[1] *= inv; w[2] *= inv; w[3] *= inv;
    *(f32x4*)(op + dt * 16) = w;
  }
}

// ---- KV cache: copy base cache, then scatter new k/v rows by slot ----
__global__ __launch_bounds__(256) void copy_caches(
    const f32x4* __restrict__ kc_in, const f32x4* __restrict__ vc_in,
    f32x4* __restrict__ kc_out, f32x4* __restrict__ vc_out)
{
  const size_t i = (size_t)blockIdx.x * 256 + threadIdx.x;
  kc_out[i] = kc_in[i];
  vc_out[i] = vc_in[i];
}

__global__ __launch_bounds__(256) void scatter_kv(
    const f32x4* __restrict__ kin, const f32x4* __restrict__ vin,
    const int* __restrict__ slot, f32x4* __restrict__ kc_out,
    f32x4* __restrict__ vc_out)
{
  const int row = blockIdx.x;
  const int s = slot[row];
  if (s < 0) return;
  const int t = threadIdx.x;  // 256 threads x float4 = 1024 floats/row
  kc_out[(size_t)s * 256 + t] = kin[(size_t)row * 256 + t];
  vc_out[(size_t)s * 256 + t] = vin[(size_t)row * 256 + t];
}

extern "C" void kernel_launch(void* const* d_in, const int* in_sizes, int n_in,
                              void* d_out, int out_size, void* d_ws, size_t ws_size,
                              hipStream_t stream) {
  const float* q  = (const float*)d_in[0];
  const float* k  = (const float*)d_in[1];
  const float* v  = (const float*)d_in[2];
  const float* kc = (const float*)d_in[3];
  const float* vc = (const float*)d_in[4];
  const int* slot = (const int*)d_in[5];

  float* out    = (float*)d_out;
  float* kc_out = out + (size_t)N_TOK * H_Q * DH;
  float* vc_out = kc_out + (size_t)N_TOK * H_KV * DH;

  copy_caches<<<dim3((N_TOK * H_KV * DH / 4) / 256), 256, 0, stream>>>(
      (const f32x4*)kc, (const f32x4*)vc, (f32x4*)kc_out, (f32x4*)vc_out);
  scatter_kv<<<dim3(N_TOK), 256, 0, stream>>>(
      (const f32x4*)k, (const f32x4*)v, slot, (f32x4*)kc_out, (f32x4*)vc_out);
  attn_fwd<<<dim3(H_KV * BATCH, NQT), 512, 0, stream>>>(q, k, v, out);
}

// Round 7
// 347.338 us; speedup vs baseline: 2.4121x; 1.1977x over previous
//
#include <hip/hip_runtime.h>
#include <hip/hip_bf16.h>
#include <stdint.h>

#define N_TOK 4096
#define H_Q   32
#define H_KV  8
#define DH    128
#define SEQ   2048
#define BATCH (N_TOK / SEQ)
#define GRP   (H_Q / H_KV)
#define QTILE 32     // q rows per block-phase (shared by 4 heads)
#define KVT   32     // kv tile
#define NQT   (SEQ / QTILE)

#define KP 136   // K_lds row pitch (bf16)
#define VP 40    // V_lds^T row pitch (bf16)
#define PP 40    // P_lds row pitch

typedef __attribute__((ext_vector_type(8))) short bf16x8;
typedef __attribute__((ext_vector_type(4))) float f32x4;
typedef __attribute__((ext_vector_type(4))) int   i32x4;

// Compiler-native RNE f32->bf16: pairs fuse to v_cvt_pk_bf16_f32 (m240).
__device__ __forceinline__ uint16_t f2bf(float x) {
  union { __hip_bfloat16 h; uint16_t u; } c;
  c.h = __float2bfloat16(x);
  return c.u;
}
__device__ __forceinline__ uint32_t pk2(float a, float b) {
  return (uint32_t)f2bf(a) | ((uint32_t)f2bf(b) << 16);
}

// Block: TWO q-tiles (pair qt = 63-y then qt = y) x 4 q-heads of one hkv
// group, processed sequentially -> every block costs exactly 65 kv-tiles
// (uniform; kills the occupancy drain measured at 30% in round 6).
// 8 waves (512 thr); wave w: head = w&3, m-tile = w>>2. KV tiles staged
// once per block-phase (K by waves 0-3, V by waves 4-7).
//
// SWAPPED MFMA: S^T = mfma(A=K, B=Q^T) -> D[kv][q]: lane owns q-row (l&15),
// 8 kv values in-register -> softmax is 7 in-lane ops + 2 shfl.
// PV: O^T = mfma(A=V^T, B=P^T) -> D[d][q] -> vectorized f32x4 stores.
__global__ __launch_bounds__(512) void attn_fwd(
    const float* __restrict__ q, const float* __restrict__ k,
    const float* __restrict__ v, float* __restrict__ out)
{
  const int xb  = blockIdx.x;
  const int hkv = xb & 7;
  const int b   = xb >> 3;
  const int yy  = blockIdx.y;          // 0..31: pair (63-yy, yy)
  const int tid = threadIdx.x;
  const int wid = tid >> 6;
  const int lane = tid & 63;
  const int lg = lane >> 4;
  const int lr = lane & 15;
  const int h  = hkv * GRP + (wid & 3);
  const int mt = wid >> 2;

  __shared__ uint16_t K_lds[KVT * KP];      // [kv][d]
  __shared__ uint16_t V_lds[DH * VP];       // [d][kv] (transposed)
  __shared__ uint16_t P_lds[8][16 * PP];    // per-wave P staging [q][kv]

  const float L2E = 1.4426950408889634f;

  for (int ph = 0; ph < 2; ++ph) {
    const int qt = ph ? yy : (NQT - 1 - yy);
    const int q0 = qt * QTILE;

    // ---- Q fragment (B-operand), pre-scaled ----
    const int qrow = q0 + mt * 16 + lr;
    bf16x8 qf[4];
    {
      const float* qp = q + ((size_t)(b * SEQ + qrow) * H_Q + h) * DH + lg * 8;
      const float sc = 0.08838834764831845f;  // 1/sqrt(128)
#pragma unroll
      for (int dblk = 0; dblk < 4; ++dblk) {
        f32x4 f0 = *(const f32x4*)(qp + dblk * 32);
        f32x4 f1 = *(const f32x4*)(qp + dblk * 32 + 4);
        i32x4 w;
        w[0] = pk2(f0[0] * sc, f0[1] * sc);
        w[1] = pk2(f0[2] * sc, f0[3] * sc);
        w[2] = pk2(f1[0] * sc, f1[1] * sc);
        w[3] = pk2(f1[2] * sc, f1[3] * sc);
        qf[dblk] = *(bf16x8*)&w;
      }
    }

    f32x4 o[8];
#pragma unroll
    for (int i = 0; i < 8; ++i) o[i] = (f32x4){0.f, 0.f, 0.f, 0.f};
    float m_i = -1e30f, l_i = 0.f;

    const int nt = qt + 1;

    for (int t = 0; t < nt; ++t) {
      const int kv0 = t * KVT;
      __syncthreads();  // protect LDS from previous iteration's readers

      if (tid < 256) {
        // ---- stage K tile [32][128] f32 -> bf16 LDS (waves 0-3) ----
        const int row = tid >> 3;
        const int c0 = (tid & 7) * 16;
        const float* kp = k + ((size_t)(b * SEQ + kv0 + row) * H_KV + hkv) * DH + c0;
        f32x4 f0 = *(const f32x4*)(kp + 0);
        f32x4 f1 = *(const f32x4*)(kp + 4);
        f32x4 f2 = *(const f32x4*)(kp + 8);
        f32x4 f3 = *(const f32x4*)(kp + 12);
        i32x4 w0, w1;
        w0[0] = pk2(f0[0], f0[1]); w0[1] = pk2(f0[2], f0[3]);
        w0[2] = pk2(f1[0], f1[1]); w0[3] = pk2(f1[2], f1[3]);
        w1[0] = pk2(f2[0], f2[1]); w1[1] = pk2(f2[2], f2[3]);
        w1[2] = pk2(f3[0], f3[1]); w1[3] = pk2(f3[2], f3[3]);
        *(i32x4*)&K_lds[row * KP + c0]     = w0;
        *(i32x4*)&K_lds[row * KP + c0 + 8] = w1;
      } else {
        // ---- stage V tile transposed [d][kv], scrambled kv-group (waves 4-7) ----
        const int t2 = tid - 256;
        const int rr = t2 & 31;             // d-group (d = 4*rr..+3)
        const int cc = t2 >> 5;             // 0..7
        const int c  = (cc + rr) & 7;       // scrambled kv-group (bijective per rr)
        const float* vp = v + ((size_t)(b * SEQ + kv0 + 4 * c) * H_KV + hkv) * DH + 4 * rr;
        const size_t vstep = (size_t)H_KV * DH;
        f32x4 r0 = *(const f32x4*)(vp);
        f32x4 r1 = *(const f32x4*)(vp + vstep);
        f32x4 r2 = *(const f32x4*)(vp + 2 * vstep);
        f32x4 r3 = *(const f32x4*)(vp + 3 * vstep);
#pragma unroll
        for (int dd = 0; dd < 4; ++dd) {
          uint2 w;
          w.x = pk2(r0[dd], r1[dd]);
          w.y = pk2(r2[dd], r3[dd]);
          *(uint2*)&V_lds[(4 * rr + dd) * VP + 4 * c] = w;
        }
      }
      __syncthreads();

      // ---- S^T = K Q^T (D[kv][q]; s0: kv0+lg*4+i, s1: +16) ----
      f32x4 s0 = (f32x4){0.f, 0.f, 0.f, 0.f};
      f32x4 s1 = (f32x4){0.f, 0.f, 0.f, 0.f};
      __builtin_amdgcn_s_setprio(1);
#pragma unroll
      for (int dblk = 0; dblk < 4; ++dblk) {
        bf16x8 kb0 = *(const bf16x8*)&K_lds[lr * KP + dblk * 32 + lg * 8];
        bf16x8 kb1 = *(const bf16x8*)&K_lds[(16 + lr) * KP + dblk * 32 + lg * 8];
        s0 = __builtin_amdgcn_mfma_f32_16x16x32_bf16(kb0, qf[dblk], s0, 0, 0, 0);
        s1 = __builtin_amdgcn_mfma_f32_16x16x32_bf16(kb1, qf[dblk], s1, 0, 0, 0);
      }
      __builtin_amdgcn_s_setprio(0);

      // ---- softmax (lane-local row); mask only on the diagonal tile ----
      float p[8];
      if (t == nt - 1) {
#pragma unroll
        for (int i = 0; i < 4; ++i) {
          p[i]     = (kv0 + lg * 4 + i      <= qrow) ? s0[i] : -1e30f;
          p[4 + i] = (kv0 + 16 + lg * 4 + i <= qrow) ? s1[i] : -1e30f;
        }
      } else {
#pragma unroll
        for (int i = 0; i < 4; ++i) { p[i] = s0[i]; p[4 + i] = s1[i]; }
      }
      float mx = fmaxf(fmaxf(fmaxf(p[0], p[1]), fmaxf(p[2], p[3])),
                       fmaxf(fmaxf(p[4], p[5]), fmaxf(p[6], p[7])));
      mx = fmaxf(mx, __shfl_xor(mx, 16));
      mx = fmaxf(mx, __shfl_xor(mx, 32));
      if (mx > m_i) {                    // exact defer: rescale only if max grew
        const float rs = exp2f((m_i - mx) * L2E);
        l_i *= rs;
#pragma unroll
        for (int dt = 0; dt < 8; ++dt) {
          o[dt][0] *= rs; o[dt][1] *= rs; o[dt][2] *= rs; o[dt][3] *= rs;
        }
        m_i = mx;
      }
#pragma unroll
      for (int j = 0; j < 8; ++j) p[j] = exp2f((p[j] - m_i) * L2E);
      float sum = ((p[0] + p[1]) + (p[2] + p[3])) + ((p[4] + p[5]) + (p[6] + p[7]));
      sum += __shfl_xor(sum, 16);
      sum += __shfl_xor(sum, 32);
      l_i += sum;

      // ---- stage P[q][kv] (per-wave, no barrier) ----
      {
        uint2 w0, w1;
        w0.x = pk2(p[0], p[1]); w0.y = pk2(p[2], p[3]);
        w1.x = pk2(p[4], p[5]); w1.y = pk2(p[6], p[7]);
        *(uint2*)&P_lds[wid][lr * PP + lg * 4]      = w0;
        *(uint2*)&P_lds[wid][lr * PP + 16 + lg * 4] = w1;
      }

      // ---- O^T += V^T P^T (D[d][q]) ----
      bf16x8 pf = *(const bf16x8*)&P_lds[wid][lr * PP + lg * 8];
      __builtin_amdgcn_s_setprio(1);
#pragma unroll
      for (int dt = 0; dt < 8; ++dt) {
        bf16x8 vb = *(const bf16x8*)&V_lds[(dt * 16 + lr) * VP + lg * 8];
        o[dt] = __builtin_amdgcn_mfma_f32_16x16x32_bf16(vb, pf, o[dt], 0, 0, 0);
      }
      __builtin_amdgcn_s_setprio(0);
    }

    // ---- epilogue: out[qrow][d] = O^T / l ; d = dt*16 + lg*4 + i ----
    const float inv = 1.0f / l_i;
    float* op = out + ((size_t)(b * SEQ + qrow) * H_Q + h) * DH + lg * 4;
#pragma unroll
    for (int dt = 0; dt < 8; ++dt) {
      f32x4 w = o[dt];
      w[0] *= inv; w[1] *= inv; w[2] *= inv; w[3] *= inv;
      *(f32x4*)(op + dt * 16) = w;
    }
    // next phase's staging is guarded by the __syncthreads() at tile-loop top
  }
}

// ---- KV cache: copy base cache, then scatter new k/v rows by slot ----
__global__ __launch_bounds__(256) void copy_caches(
    const f32x4* __restrict__ kc_in, const f32x4* __restrict__ vc_in,
    f32x4* __restrict__ kc_out, f32x4* __restrict__ vc_out)
{
  const size_t i = (size_t)blockIdx.x * 256 + threadIdx.x;
  kc_out[i] = kc_in[i];
  vc_out[i] = vc_in[i];
}

__global__ __launch_bounds__(256) void scatter_kv(
    const f32x4* __restrict__ kin, const f32x4* __restrict__ vin,
    const int* __restrict__ slot, f32x4* __restrict__ kc_out,
    f32x4* __restrict__ vc_out)
{
  const int row = blockIdx.x;
  const int s = slot[row];
  if (s < 0) return;
  const int t = threadIdx.x;  // 256 threads x float4 = 1024 floats/row
  kc_out[(size_t)s * 256 + t] = kin[(size_t)row * 256 + t];
  vc_out[(size_t)s * 256 + t] = vin[(size_t)row * 256 + t];
}

extern "C" void kernel_launch(void* const* d_in, const int* in_sizes, int n_in,
                              void* d_out, int out_size, void* d_ws, size_t ws_size,
                              hipStream_t stream) {
  const float* q  = (const float*)d_in[0];
  const float* k  = (const float*)d_in[1];
  const float* v  = (const float*)d_in[2];
  const float* kc = (const float*)d_in[3];
  const float* vc = (const float*)d_in[4];
  const int* slot = (const int*)d_in[5];

  float* out    = (float*)d_out;
  float* kc_out = out + (size_t)N_TOK * H_Q * DH;
  float* vc_out = kc_out + (size_t)N_TOK * H_KV * DH;

  copy_caches<<<dim3((N_TOK * H_KV * DH / 4) / 256), 256, 0, stream>>>(
      (const f32x4*)kc, (const f32x4*)vc, (f32x4*)kc_out, (f32x4*)vc_out);
  scatter_kv<<<dim3(N_TOK), 256, 0, stream>>>(
      (const f32x4*)k, (const f32x4*)v, slot, (f32x4*)kc_out, (f32x4*)vc_out);
  attn_fwd<<<dim3(H_KV * BATCH, NQT / 2), 512, 0, stream>>>(q, k, v, out);
}